// Round 6
// baseline (138.626 us; speedup 1.0000x reference)
//
#include <hip/hip_runtime.h>

#define SCALE 0.044194173824159216f   // 1/sqrt(512)

typedef _Float16 half8 __attribute__((ext_vector_type(8)));
typedef _Float16 half4 __attribute__((ext_vector_type(4)));
typedef float    f32x4 __attribute__((ext_vector_type(4)));

#define MFMA(A, B, Cc) __builtin_amdgcn_mfma_f32_16x16x32_f16((A), (B), (Cc), 0, 0, 0)

// ---------------- ws layout (bytes) ----------------
#define X16_OFF 0ull
#define Q16_OFF 33554432ull
#define K16_OFF 67108864ull
#define VT_OFF  100663296ull
#define W16_OFF 134217728ull    // W_all fp16 [1536][512]: Wq~(scaled), Wk, Wv
#define WS_NEED 135790592ull

typedef __attribute__((address_space(1))) const unsigned int glb_t;
typedef __attribute__((address_space(3))) unsigned int lds_t;

// async global->LDS, 16B per lane; LDS dest = wave-uniform base + lane*16
__device__ __forceinline__ void gl16(const void* g, void* l) {
  __builtin_amdgcn_global_load_lds((glb_t*)g, (lds_t*)l, 16, 0, 0);
}

// swizzled read of a [R][64] fp16 tile (row stride 128B): LDS[row][u16] = glob[row][u16^(row&7)]
__device__ __forceinline__ half8 ldf64(const _Float16* buf, int row, int colh) {
  int byte = row * 128 + (((colh) << 1) ^ ((row & 7) << 4));
  return *(const half8*)((const char*)buf + byte);
}
// swizzled read of a [R][128] fp16 tile (row stride 256B)
__device__ __forceinline__ half8 ldf128(const _Float16* buf, int row, int colh) {
  int byte = row * 256 + (((colh) << 1) ^ ((row & 7) << 4));
  return *(const half8*)((const char*)buf + byte);
}

// ================= K0: fp32 -> fp16 convert (x; W with 1/sqrt(D) folded into Wq) =================
__global__ __launch_bounds__(256)
void k0_cvt(const float* __restrict__ x, const float* __restrict__ Wq,
            const float* __restrict__ Wk, const float* __restrict__ Wv,
            _Float16* __restrict__ x16, _Float16* __restrict__ w16)
{
  const long long NX = 16777216LL;   // 4*8192*512
  long long base = ((long long)blockIdx.x * 256 + threadIdx.x) * 8;
  const float* src;
  _Float16* dst;
  float sc = 1.0f;
  if (base < NX) {
    src = x + base; dst = x16 + base;
  } else {
    long long o = base - NX;             // 0 .. 786431
    int ws = (int)(o >> 18);
    long long oo = o & 262143LL;
    src = (ws == 0 ? Wq : (ws == 1 ? Wk : Wv)) + oo;
    dst = w16 + o;
    if (ws == 0) sc = SCALE;
  }
  const float4* p = (const float4*)src;
  float4 f0 = p[0], f1 = p[1];
  half8 v;
  v[0] = (_Float16)(f0.x * sc); v[1] = (_Float16)(f0.y * sc);
  v[2] = (_Float16)(f0.z * sc); v[3] = (_Float16)(f0.w * sc);
  v[4] = (_Float16)(f1.x * sc); v[5] = (_Float16)(f1.y * sc);
  v[6] = (_Float16)(f1.z * sc); v[7] = (_Float16)(f1.w * sc);
  *(half8*)dst = v;
}

// ================= K1: 256x256 GEMM, 8 waves, 4-phase/K-tile deep pipeline =================
// C = x16[32768,512] @ W_all[1536,512]^T ; ntile 0..1 -> q, 2..3 -> k, 4..5 -> vT(transposed)
//
// LDS phys layouts (per parity, fp16, row stride 128B, XOR-swizzled 16B units):
//  A: phys = mh*128 + wm*64 + (m&63)   (mh = half, wm = wave-row)   g(phys) = wm*128 + mh*64 + r63
//  B: phys = nh*128 + wn*32 + (g&31)                                g(phys) = wn*64 + nh*32 + w31
// Half-tile stream order per K-tile: S0=A0(slabs0,1) S1=B0(0,1) S2=B1(2,3) S3=A1(2,3);
// phase q of K-tile t stages S(4(t+1)+q); end-of-phase vmcnt(4)/(4)/none/(4) keeps >=2 HTs in flight.
__global__ __launch_bounds__(512, 2)
void k1_gemm(const _Float16* __restrict__ x16, const _Float16* __restrict__ w16,
             _Float16* __restrict__ q16, _Float16* __restrict__ k16,
             _Float16* __restrict__ vT)
{
  __shared__ _Float16 As[2][16384];   // 2 x 32KB
  __shared__ _Float16 Bs[2][16384];   // 2 x 32KB   (total 128KB)

  // bijective XCD swizzle: 768 blocks = 8 XCDs x 96; contiguous (stile x 6 ntiles) per XCD
  const int id  = blockIdx.x;
  const int swz = (id & 7) * 96 + (id >> 3);
  const int ntile = swz % 6;
  const int stile = swz / 6;
  const int wsel  = ntile >> 1;
  const bool vpath = (wsel == 2);

  const int tid = threadIdx.x, lane = tid & 63, w = tid >> 6;
  const int l15 = lane & 15, h = lane >> 4;
  const int wm = w >> 2, wn = w & 3;          // 2 x 4 wave grid; wave output 128m x 64n

  const _Float16* xb = x16 + (size_t)stile * 256 * 512;
  const _Float16* wb = w16 + (size_t)ntile * 256 * 512;

  // staging maps: issue covers 64 phys rows x 8 units; thread -> (t6, u8)
  const int t6 = tid >> 3, u8 = tid & 7;
  const int colsw = ((u8 ^ (t6 & 7)) << 3);   // inverse-swizzled source col (fp16 elems)
  const int gA[4] = { t6, 128 + t6, 64 + t6, 192 + t6 };
  int gB[4];
  #pragma unroll
  for (int i = 0; i < 4; ++i) {
    int pp = i * 64 + t6;
    gB[i] = (((pp >> 5) & 3) << 6) + ((pp >> 7) << 5) + (pp & 31);
  }

#define STAGE_A2(par, i0, kc)                                                      \
  { gl16(xb + (size_t)gA[i0] * 512 + (kc) + colsw, &As[par][((i0)*512 + w*64)*8]); \
    gl16(xb + (size_t)gA[(i0)+1] * 512 + (kc) + colsw, &As[par][(((i0)+1)*512 + w*64)*8]); }
#define STAGE_B2(par, i0, kc)                                                      \
  { gl16(wb + (size_t)gB[i0] * 512 + (kc) + colsw, &Bs[par][((i0)*512 + w*64)*8]); \
    gl16(wb + (size_t)gB[(i0)+1] * 512 + (kc) + colsw, &Bs[par][(((i0)+1)*512 + w*64)*8]); }

  f32x4 acc[8][4] = {};
  half8 af[8], bf0[4], bf1[4];

  // prologue: K-tile 0 into parity 0, stream order S0,S1,S2,S3
  STAGE_A2(0, 0, 0);
  STAGE_B2(0, 0, 0);
  STAGE_B2(0, 2, 0);
  STAGE_A2(0, 2, 0);
  asm volatile("s_waitcnt vmcnt(4)" ::: "memory");   // S0,S1 (A0,B0) landed
  __builtin_amdgcn_s_barrier();
  __builtin_amdgcn_sched_barrier(0);

  for (int t = 0; t < 8; ++t) {
    const int p = t & 1, np = p ^ 1;
    const _Float16* Ap = As[p];
    const _Float16* Bp = Bs[p];
    const int kc = (t + 1) * 64;
    const bool stg = (t < 7);

    // -------- phase 0: Q(mh0,nh0); stage A0' --------
    if (stg) STAGE_A2(np, 0, kc);
    #pragma unroll
    for (int m = 0; m < 4; ++m)
      #pragma unroll
      for (int ks = 0; ks < 2; ++ks)
        af[m*2+ks] = ldf64(Ap, wm*64 + m*16 + l15, ks*32 + h*8);
    #pragma unroll
    for (int n = 0; n < 2; ++n)
      #pragma unroll
      for (int ks = 0; ks < 2; ++ks)
        bf0[n*2+ks] = ldf64(Bp, wn*32 + n*16 + l15, ks*32 + h*8);
    __builtin_amdgcn_s_barrier();
    __builtin_amdgcn_s_setprio(1);
    #pragma unroll
    for (int m = 0; m < 4; ++m)
      #pragma unroll
      for (int n = 0; n < 2; ++n)
        #pragma unroll
        for (int ks = 0; ks < 2; ++ks)
          acc[m][n] = vpath ? MFMA(bf0[n*2+ks], af[m*2+ks], acc[m][n])
                            : MFMA(af[m*2+ks], bf0[n*2+ks], acc[m][n]);
    __builtin_amdgcn_s_setprio(0);
    if (stg) { asm volatile("s_waitcnt vmcnt(4)" ::: "memory"); }
    else     { asm volatile("s_waitcnt vmcnt(2)" ::: "memory"); }
    __builtin_amdgcn_s_barrier();
    __builtin_amdgcn_sched_barrier(0);

    // -------- phase 1: Q(mh0,nh1); stage B0' --------
    if (stg) STAGE_B2(np, 0, kc);
    #pragma unroll
    for (int n = 0; n < 2; ++n)
      #pragma unroll
      for (int ks = 0; ks < 2; ++ks)
        bf1[n*2+ks] = ldf64(Bp, 128 + wn*32 + n*16 + l15, ks*32 + h*8);
    __builtin_amdgcn_s_barrier();
    __builtin_amdgcn_s_setprio(1);
    #pragma unroll
    for (int m = 0; m < 4; ++m)
      #pragma unroll
      for (int n = 0; n < 2; ++n)
        #pragma unroll
        for (int ks = 0; ks < 2; ++ks)
          acc[m][2+n] = vpath ? MFMA(bf1[n*2+ks], af[m*2+ks], acc[m][2+n])
                              : MFMA(af[m*2+ks], bf1[n*2+ks], acc[m][2+n]);
    __builtin_amdgcn_s_setprio(0);
    if (stg) { asm volatile("s_waitcnt vmcnt(4)" ::: "memory"); }
    else     { asm volatile("s_waitcnt vmcnt(0)" ::: "memory"); }
    __builtin_amdgcn_s_barrier();
    __builtin_amdgcn_sched_barrier(0);

    // -------- phase 2: Q(mh1,nh1); stage B1' --------
    if (stg) STAGE_B2(np, 2, kc);
    #pragma unroll
    for (int m = 0; m < 4; ++m)
      #pragma unroll
      for (int ks = 0; ks < 2; ++ks)
        af[m*2+ks] = ldf64(Ap, 128 + wm*64 + m*16 + l15, ks*32 + h*8);
    __builtin_amdgcn_s_barrier();
    __builtin_amdgcn_s_setprio(1);
    #pragma unroll
    for (int m = 0; m < 4; ++m)
      #pragma unroll
      for (int n = 0; n < 2; ++n)
        #pragma unroll
        for (int ks = 0; ks < 2; ++ks)
          acc[4+m][2+n] = vpath ? MFMA(bf1[n*2+ks], af[m*2+ks], acc[4+m][2+n])
                                : MFMA(af[m*2+ks], bf1[n*2+ks], acc[4+m][2+n]);
    __builtin_amdgcn_s_setprio(0);
    __builtin_amdgcn_s_barrier();
    __builtin_amdgcn_sched_barrier(0);

    // -------- phase 3: Q(mh1,nh0); stage A1' (no ds_reads; bf0 reused) --------
    if (stg) STAGE_A2(np, 2, kc);
    __builtin_amdgcn_s_barrier();
    __builtin_amdgcn_s_setprio(1);
    #pragma unroll
    for (int m = 0; m < 4; ++m)
      #pragma unroll
      for (int n = 0; n < 2; ++n)
        #pragma unroll
        for (int ks = 0; ks < 2; ++ks)
          acc[4+m][n] = vpath ? MFMA(bf0[n*2+ks], af[m*2+ks], acc[4+m][n])
                              : MFMA(af[m*2+ks], bf0[n*2+ks], acc[4+m][n]);
    __builtin_amdgcn_s_setprio(0);
    if (stg) { asm volatile("s_waitcnt vmcnt(4)" ::: "memory"); }
    __builtin_amdgcn_s_barrier();
    __builtin_amdgcn_sched_barrier(0);
  }
#undef STAGE_A2
#undef STAGE_B2

  if (!vpath) {
    _Float16* dst = (wsel == 0) ? q16 : k16;
    const int m0 = stile * 256 + wm * 128;
    const int n0 = (ntile & 1) * 256 + wn * 64;
    #pragma unroll
    for (int mf = 0; mf < 8; ++mf)
      #pragma unroll
      for (int nf = 0; nf < 4; ++nf)
        #pragma unroll
        for (int r = 0; r < 4; ++r)
          dst[(size_t)(m0 + mf * 16 + h * 4 + r) * 512 + n0 + nf * 16 + l15] =
              (_Float16)acc[mf][nf][r];
  } else {
    const int d0 = (ntile & 1) * 256 + wn * 64;
    const int sg = stile * 256 + wm * 128;
    const int bb = sg >> 13, s0 = sg & 8191;
    _Float16* dst = vT + (size_t)bb * 512 * 8192;
    #pragma unroll
    for (int mf = 0; mf < 8; ++mf)
      #pragma unroll
      for (int nf = 0; nf < 4; ++nf)
        #pragma unroll
        for (int r = 0; r < 4; ++r)
          dst[(size_t)(d0 + nf * 16 + h * 4 + r) * 8192 + s0 + mf * 16 + l15] =
              (_Float16)acc[mf][nf][r];
  }
}

// ================= K2: chunked attention, 4 waves per (b,c), staged k/vT, XCD-chunked =================
__global__ __launch_bounds__(256)
void k2_attn(const _Float16* __restrict__ q16, const _Float16* __restrict__ k16,
             const _Float16* __restrict__ vT, float* __restrict__ out)
{
  __shared__ _Float16 kj[2][128 * 64];   // 2x16KB: S: [128 j][64 e] ; PV: [64 d][128 j]
  __shared__ _Float16 p_lds[64 * 128];   // 16KB, [64 q][128 j], swizzled, wave-local use

  const int id = blockIdx.x;             // 512 blocks = 8 XCDs x 64; contiguous c per XCD
  const int sz = (id & 7) * 64 + (id >> 3);
  const int b = sz >> 7, c = sz & 127;
  const int tid = threadIdx.x, lane = tid & 63, w = tid >> 6;
  const int l15 = lane & 15, h = lane >> 4;
  const int jbase = c * 64 - 64;

  const _Float16* qrow = q16 + (size_t)(b * 8192 + c * 64 + w * 16 + l15) * 512;
  half8 qa[16];
  #pragma unroll
  for (int ks = 0; ks < 16; ++ks) qa[ks] = *(const half8*)(qrow + ks * 32 + h * 8);

  const _Float16* kb = k16 + (size_t)b * 8192 * 512;

  // ---- S phase: e-loop, double-buffered k-slices ----
  f32x4 S[8] = {};
  {
    #pragma unroll
    for (int i = 0; i < 4; ++i) {
      int unit = i * 256 + w * 64 + lane;
      int row = unit >> 3, u = unit & 7;
      int sj = jbase + row; if (sj < 0) sj = 0;
      gl16(kb + (size_t)sj * 512 + ((u ^ (row & 7)) << 3), &kj[0][(i * 256 + w * 64) * 8]);
    }
    int cur = 0;
    for (int ee = 0; ee < 8; ++ee) {
      __syncthreads();                 // drain stage(cur); waves done reading cur^1
      if (ee < 7) {
        #pragma unroll
        for (int i = 0; i < 4; ++i) {
          int unit = i * 256 + w * 64 + lane;
          int row = unit >> 3, u = unit & 7;
          int sj = jbase + row; if (sj < 0) sj = 0;
          gl16(kb + (size_t)sj * 512 + (ee + 1) * 64 + ((u ^ (row & 7)) << 3),
               &kj[cur ^ 1][(i * 256 + w * 64) * 8]);
        }
      }
      #pragma unroll
      for (int ks = 0; ks < 2; ++ks) {
        #pragma unroll
        for (int nt = 0; nt < 8; ++nt) {
          half8 bf = ldf64(kj[cur], nt * 16 + l15, ks * 32 + h * 8);
          S[nt] = MFMA(qa[ee * 2 + ks], bf, S[nt]);
        }
      }
      cur ^= 1;
    }
  }

  // ---- masked softmax ----
  #pragma unroll
  for (int jt = 0; jt < 8; ++jt) {
    int j = jt * 16 + l15;
    #pragma unroll
    for (int r = 0; r < 4; ++r) {
      int ql = w * 16 + h * 4 + r;
      bool valid = (j < 64 + ql) && ((c > 0) || (j >= 64));
      S[jt][r] = valid ? S[jt][r] : -1e30f;
    }
  }
  #pragma unroll
  for (int r = 0; r < 4; ++r) {
    float mx = -1e30f;
    #pragma unroll
    for (int jt = 0; jt < 8; ++jt) mx = fmaxf(mx, S[jt][r]);
    mx = fmaxf(mx, __shfl_xor(mx, 1));
    mx = fmaxf(mx, __shfl_xor(mx, 2));
    mx = fmaxf(mx, __shfl_xor(mx, 4));
    mx = fmaxf(mx, __shfl_xor(mx, 8));
    float sum = 0.f;
    #pragma unroll
    for (int jt = 0; jt < 8; ++jt) {
      float sv = S[jt][r];
      float pe = (sv > -1e29f) ? __expf(sv - mx) : 0.f;
      S[jt][r] = pe;
      sum += pe;
    }
    sum += __shfl_xor(sum, 1);
    sum += __shfl_xor(sum, 2);
    sum += __shfl_xor(sum, 4);
    sum += __shfl_xor(sum, 8);
    float inv = (sum > 0.f) ? (1.0f / sum) : 0.f;   // fully-masked row -> p = 0
    #pragma unroll
    for (int jt = 0; jt < 8; ++jt) {
      int row = w * 16 + h * 4 + r, col = jt * 16 + l15;
      _Float16 ph = (_Float16)(S[jt][r] * inv);
      *(_Float16*)((char*)p_lds + row * 256 + ((col << 1) ^ ((row & 7) << 4))) = ph;
    }
  }
  half8 pa[4];
  #pragma unroll
  for (int ks = 0; ks < 4; ++ks) {
    int row = w * 16 + l15, colh = ks * 32 + h * 8;
    pa[ks] = *(const half8*)((const char*)p_lds + row * 256 + ((colh << 1) ^ ((row & 7) << 4)));
  }

  // ---- PV phase: d-loop, double-buffered vT-slices [64 d][128 j] ----
  const _Float16* vb = vT + (size_t)b * 512 * 8192;
  float* ob = out + (size_t)(b * 8192 + c * 64 + w * 16) * 512;

  __syncthreads();
  #pragma unroll
  for (int i = 0; i < 4; ++i) {
    int unit = i * 256 + w * 64 + lane;
    int row = unit >> 4, u = unit & 15;
    int u2 = (u & 8) | ((u & 7) ^ (row & 7));
    int js = jbase + u2 * 8; if (js < 0) js = 0;
    gl16(vb + (size_t)row * 8192 + js, &kj[0][(i * 256 + w * 64) * 8]);
  }
  int cur = 0;
  for (int dd = 0; dd < 8; ++dd) {
    __syncthreads();
    if (dd < 7) {
      #pragma unroll
      for (int i = 0; i < 4; ++i) {
        int unit = i * 256 + w * 64 + lane;
        int row = unit >> 4, u = unit & 15;
        int u2 = (u & 8) | ((u & 7) ^ (row & 7));
        int js = jbase + u2 * 8; if (js < 0) js = 0;
        gl16(vb + (size_t)((dd + 1) * 64 + row) * 8192 + js, &kj[cur ^ 1][(i * 256 + w * 64) * 8]);
      }
    }
    f32x4 o[4] = {};
    #pragma unroll
    for (int ks = 0; ks < 4; ++ks) {
      #pragma unroll
      for (int nr = 0; nr < 4; ++nr) {
        half8 bf = ldf128(kj[cur], nr * 16 + l15, ks * 32 + h * 8);
        o[nr] = MFMA(pa[ks], bf, o[nr]);
      }
    }
    #pragma unroll
    for (int nr = 0; nr < 4; ++nr)
      #pragma unroll
      for (int r = 0; r < 4; ++r)
        ob[(size_t)(h * 4 + r) * 512 + dd * 64 + nr * 16 + l15] = o[nr][r];
    cur ^= 1;
  }
}

// ================= fallback: round-1 fused kernel (used only if ws too small) =================
__device__ __forceinline__ int swzb(int row, int colByte) {
  return colByte ^ ((row & 7) << 4);
}
__device__ __forceinline__ half8 ldw_frag(const float* __restrict__ W, int row, int e0) {
  const float4* p = reinterpret_cast<const float4*>(W + ((size_t)row << 9) + e0);
  float4 f0 = p[0];
  float4 f1 = p[1];
  half8 v;
  v[0] = (_Float16)f0.x; v[1] = (_Float16)f0.y; v[2] = (_Float16)f0.z; v[3] = (_Float16)f0.w;
  v[4] = (_Float16)f1.x; v[5] = (_Float16)f1.y; v[6] = (_Float16)f1.z; v[7] = (_Float16)f1.w;
  return v;
}
__device__ __forceinline__ half8 ldl_frag(const unsigned short* buf, int row, int col, int strideBytes) {
  int byte = row * strideBytes + swzb(row, col << 1);
  return *reinterpret_cast<const half8*>(reinterpret_cast<const char*>(buf) + byte);
}

__global__ __launch_bounds__(256, 1)
void ep_fused(const float* __restrict__ x, const float* __restrict__ Wq,
              const float* __restrict__ Wk, const float* __restrict__ Wv,
              float* __restrict__ out)
{
  __shared__ unsigned short xs[128 * 512];
  __shared__ unsigned short kv[64 * 128];
  __shared__ unsigned short pq[64 * 128];

  const int bc   = blockIdx.x;
  const int b    = bc >> 7;
  const int c    = bc & 127;
  const int tid  = threadIdx.x;
  const int lane = tid & 63;
  const int w    = tid >> 6;
  const int l15  = lane & 15;
  const int h    = lane >> 4;

  const float* xb = x + (size_t)b * (8192 * 512);
  #pragma unroll
  for (int i = 0; i < 32; ++i) {
    int unit = tid + (i << 8);
    int row  = unit >> 6;
    int e0   = (unit & 63) << 3;
    half8 v;
    if (c == 0 && row < 64) {
      #pragma unroll
      for (int t = 0; t < 8; ++t) v[t] = (_Float16)0.0f;
    } else {
      int s = c * 64 - 64 + row;
      const float4* p = reinterpret_cast<const float4*>(xb + (size_t)s * 512 + e0);
      float4 f0 = p[0], f1 = p[1];
      v[0] = (_Float16)f0.x; v[1] = (_Float16)f0.y; v[2] = (_Float16)f0.z; v[3] = (_Float16)f0.w;
      v[4] = (_Float16)f1.x; v[5] = (_Float16)f1.y; v[6] = (_Float16)f1.z; v[7] = (_Float16)f1.w;
    }
    int byte = (row << 10) + swzb(row, e0 << 1);
    *reinterpret_cast<half8*>(reinterpret_cast<char*>(xs) + byte) = v;
  }
  __syncthreads();

  f32x4 Sacc[8] = {};
  const int d0 = (w << 4) + (h << 2);

  for (int dt = 0; dt < 8; ++dt) {
    const int drow = (dt << 6) + (w << 4) + l15;

    f32x4 qa[4] = {};
    for (int ks = 0; ks < 16; ++ks) {
      half8 a = ldw_frag(Wq, drow, (ks << 5) + (h << 3));
      #pragma unroll
      for (int nt = 0; nt < 4; ++nt) {
        half8 bf = ldl_frag(xs, 64 + (nt << 4) + l15, (ks << 5) + (h << 3), 1024);
        qa[nt] = MFMA(a, bf, qa[nt]);
      }
    }
    #pragma unroll
    for (int nt = 0; nt < 4; ++nt) {
      int q = (nt << 4) + l15;
      half4 hv;
      hv[0] = (_Float16)qa[nt][0]; hv[1] = (_Float16)qa[nt][1];
      hv[2] = (_Float16)qa[nt][2]; hv[3] = (_Float16)qa[nt][3];
      *reinterpret_cast<half4*>(reinterpret_cast<char*>(pq) + q * 128 + swzb(q, d0 << 1)) = hv;
    }

    f32x4 ka[8] = {};
    for (int ks = 0; ks < 16; ++ks) {
      half8 a = ldw_frag(Wk, drow, (ks << 5) + (h << 3));
      #pragma unroll
      for (int nt = 0; nt < 8; ++nt) {
        half8 bf = ldl_frag(xs, (nt << 4) + l15, (ks << 5) + (h << 3), 1024);
        ka[nt] = MFMA(a, bf, ka[nt]);
      }
    }
    #pragma unroll
    for (int nt = 0; nt < 8; ++nt) {
      int j = (nt << 4) + l15;
      half4 hv;
      hv[0] = (_Float16)ka[nt][0]; hv[1] = (_Float16)ka[nt][1];
      hv[2] = (_Float16)ka[nt][2]; hv[3] = (_Float16)ka[nt][3];
      *reinterpret_cast<half4*>(reinterpret_cast<char*>(kv) + j * 128 + swzb(j, d0 << 1)) = hv;
    }
    __syncthreads();

    #pragma unroll
    for (int ksd = 0; ksd < 2; ++ksd) {
      half8 a = ldl_frag(pq, (w << 4) + l15, (ksd << 5) + (h << 3), 128);
      #pragma unroll
      for (int nt = 0; nt < 8; ++nt) {
        half8 bf = ldl_frag(kv, (nt << 4) + l15, (ksd << 5) + (h << 3), 128);
        Sacc[nt] = MFMA(a, bf, Sacc[nt]);
      }
    }
    __syncthreads();
  }

  const float scale = SCALE;
  #pragma unroll
  for (int nt = 0; nt < 8; ++nt) {
    int j = (nt << 4) + l15;
    #pragma unroll
    for (int r = 0; r < 4; ++r) {
      int qrow = (w << 4) + (h << 2) + r;
      bool valid = (j < 64 + qrow) && ((c > 0) || (j >= 64));
      Sacc[nt][r] = valid ? Sacc[nt][r] * scale : -1e30f;
    }
  }
  float inv[4];
  #pragma unroll
  for (int r = 0; r < 4; ++r) {
    float mx = -1e30f;
    #pragma unroll
    for (int nt = 0; nt < 8; ++nt) mx = fmaxf(mx, Sacc[nt][r]);
    mx = fmaxf(mx, __shfl_xor(mx, 1));
    mx = fmaxf(mx, __shfl_xor(mx, 2));
    mx = fmaxf(mx, __shfl_xor(mx, 4));
    mx = fmaxf(mx, __shfl_xor(mx, 8));
    float sum = 0.f;
    #pragma unroll
    for (int nt = 0; nt < 8; ++nt) {
      float sv = Sacc[nt][r];
      float pe = (sv > -1e29f) ? __expf(sv - mx) : 0.f;
      Sacc[nt][r] = pe;
      sum += pe;
    }
    sum += __shfl_xor(sum, 1);
    sum += __shfl_xor(sum, 2);
    sum += __shfl_xor(sum, 4);
    sum += __shfl_xor(sum, 8);
    inv[r] = (sum > 0.f) ? (1.0f / sum) : 0.f;
  }
  #pragma unroll
  for (int nt = 0; nt < 8; ++nt) {
    int j = (nt << 4) + l15;
    #pragma unroll
    for (int r = 0; r < 4; ++r) {
      int qrow = (w << 4) + (h << 2) + r;
      _Float16 ph = (_Float16)(Sacc[nt][r] * inv[r]);
      *reinterpret_cast<_Float16*>(reinterpret_cast<char*>(pq) + qrow * 256 + swzb(qrow, j << 1)) = ph;
    }
  }
  __syncthreads();

  for (int dt = 0; dt < 8; ++dt) {
    const int dcol = (dt << 6) + (w << 4) + l15;

    f32x4 va[8] = {};
    for (int ks = 0; ks < 16; ++ks) {
      half8 bf = ldw_frag(Wv, dcol, (ks << 5) + (h << 3));
      #pragma unroll
      for (int mt = 0; mt < 8; ++mt) {
        half8 a = ldl_frag(xs, (mt << 4) + l15, (ks << 5) + (h << 3), 1024);
        va[mt] = MFMA(a, bf, va[mt]);
      }
    }
    {
      int dl = (w << 4) + l15;
      #pragma unroll
      for (int mt = 0; mt < 8; ++mt) {
        int j0 = (mt << 4) + (h << 2);
        half4 hv;
        hv[0] = (_Float16)va[mt][0]; hv[1] = (_Float16)va[mt][1];
        hv[2] = (_Float16)va[mt][2]; hv[3] = (_Float16)va[mt][3];
        *reinterpret_cast<half4*>(reinterpret_cast<char*>(kv) + dl * 256 + swzb(dl, j0 << 1)) = hv;
      }
    }
    __syncthreads();

    f32x4 oa[4] = {};
    #pragma unroll
    for (int ks = 0; ks < 4; ++ks) {
      half8 a = ldl_frag(pq, (w << 4) + l15, (ks << 5) + (h << 3), 256);
      #pragma unroll
      for (int nt = 0; nt < 4; ++nt) {
        half8 bf = ldl_frag(kv, (nt << 4) + l15, (ks << 5) + (h << 3), 256);
        oa[nt] = MFMA(a, bf, oa[nt]);
      }
    }
    #pragma unroll
    for (int nt = 0; nt < 4; ++nt) {
      int d = (dt << 6) + (nt << 4) + l15;
      #pragma unroll
      for (int r = 0; r < 4; ++r) {
        int qrow = (w << 4) + (h << 2) + r;
        out[((size_t)(b * 8192 + (c << 6) + qrow) << 9) + d] = oa[nt][r];
      }
    }
    __syncthreads();
  }
}

extern "C" void kernel_launch(void* const* d_in, const int* in_sizes, int n_in,
                              void* d_out, int out_size, void* d_ws, size_t ws_size,
                              hipStream_t stream) {
  const float* x  = (const float*)d_in[0];
  const float* Wq = (const float*)d_in[1];
  const float* Wk = (const float*)d_in[2];
  const float* Wv = (const float*)d_in[3];
  float* out = (float*)d_out;
  (void)in_sizes; (void)n_in; (void)out_size;

  if (d_ws != nullptr && ws_size >= WS_NEED) {
    char* ws = (char*)d_ws;
    _Float16* x16 = (_Float16*)(ws + X16_OFF);
    _Float16* q16 = (_Float16*)(ws + Q16_OFF);
    _Float16* k16 = (_Float16*)(ws + K16_OFF);
    _Float16* vT  = (_Float16*)(ws + VT_OFF);
    _Float16* w16 = (_Float16*)(ws + W16_OFF);

    hipLaunchKernelGGL(k0_cvt, dim3(8576), dim3(256), 0, stream, x, Wq, Wk, Wv, x16, w16);
    hipLaunchKernelGGL(k1_gemm, dim3(768), dim3(512), 0, stream, x16, w16, q16, k16, vT);
    hipLaunchKernelGGL(k2_attn, dim3(512), dim3(256), 0, stream, q16, k16, vT, out);
  } else {
    hipLaunchKernelGGL(ep_fused, dim3(512), dim3(256), 0, stream, x, Wq, Wk, Wv, out);
  }
}

// Round 7
// 127.365 us; speedup vs baseline: 1.0884x; 1.0884x over previous
//
#include <hip/hip_runtime.h>

#define SCALE 0.044194173824159216f   // 1/sqrt(512)

typedef _Float16 half8 __attribute__((ext_vector_type(8)));
typedef _Float16 half4 __attribute__((ext_vector_type(4)));
typedef float    f32x4 __attribute__((ext_vector_type(4)));

#define MFMA(A, B, Cc) __builtin_amdgcn_mfma_f32_16x16x32_f16((A), (B), (Cc), 0, 0, 0)

// ---------------- ws layout (bytes) ----------------
#define X16_OFF 0ull
#define Q16_OFF 33554432ull
#define K16_OFF 67108864ull
#define VT_OFF  100663296ull
#define W16_OFF 134217728ull    // W_all fp16 [1536][512]: Wq~(scaled), Wk, Wv
#define WS_NEED 135790592ull

typedef __attribute__((address_space(1))) const unsigned int glb_t;
typedef __attribute__((address_space(3))) unsigned int lds_t;

// async global->LDS, 16B per lane; LDS dest = wave-uniform base + lane*16
__device__ __forceinline__ void gl16(const void* g, void* l) {
  __builtin_amdgcn_global_load_lds((glb_t*)g, (lds_t*)l, 16, 0, 0);
}

// swizzled read of a [R][64] fp16 tile (row stride 128B): LDS[row][u16] = glob[row][u16^(row&7)]
__device__ __forceinline__ half8 ldf64(const _Float16* buf, int row, int colh) {
  int byte = row * 128 + (((colh) << 1) ^ ((row & 7) << 4));
  return *(const half8*)((const char*)buf + byte);
}
// swizzled read of a [R][128] fp16 tile (row stride 256B)
__device__ __forceinline__ half8 ldf128(const _Float16* buf, int row, int colh) {
  int byte = row * 256 + (((colh) << 1) ^ ((row & 7) << 4));
  return *(const half8*)((const char*)buf + byte);
}

// ================= K0: fp32 -> fp16 convert (x; W with 1/sqrt(D) folded into Wq) =================
__global__ __launch_bounds__(256)
void k0_cvt(const float* __restrict__ x, const float* __restrict__ Wq,
            const float* __restrict__ Wk, const float* __restrict__ Wv,
            _Float16* __restrict__ x16, _Float16* __restrict__ w16)
{
  const long long NX = 16777216LL;   // 4*8192*512
  long long base = ((long long)blockIdx.x * 256 + threadIdx.x) * 8;
  const float* src;
  _Float16* dst;
  float sc = 1.0f;
  if (base < NX) {
    src = x + base; dst = x16 + base;
  } else {
    long long o = base - NX;             // 0 .. 786431
    int ws = (int)(o >> 18);
    long long oo = o & 262143LL;
    src = (ws == 0 ? Wq : (ws == 1 ? Wk : Wv)) + oo;
    dst = w16 + o;
    if (ws == 0) sc = SCALE;
  }
  const float4* p = (const float4*)src;
  float4 f0 = p[0], f1 = p[1];
  half8 v;
  v[0] = (_Float16)(f0.x * sc); v[1] = (_Float16)(f0.y * sc);
  v[2] = (_Float16)(f0.z * sc); v[3] = (_Float16)(f0.w * sc);
  v[4] = (_Float16)(f1.x * sc); v[5] = (_Float16)(f1.y * sc);
  v[6] = (_Float16)(f1.z * sc); v[7] = (_Float16)(f1.w * sc);
  *(half8*)dst = v;
}

// ================= K1: 256x256 GEMM, 8 waves, deep-flight 4-phase/K-tile (m201-style) =================
// C = x16[32768,512] @ W_all[1536,512]^T ; ntile 0..1 -> q, 2..3 -> k, 4..5 -> vT(transposed)
//
// Half-tile (HT) stream: s = 4*t + {0:A0,1:B0,2:B1,3:A1}, parity = t&1.
// HT s staged at phase (s-5)  -> 4-5 phases (~1000+ cyc) of flight.
// Phase (t,q): stage 1 HT -> vmcnt(8 counted; taper 4/2/0 at t=7) -> barrier(publish)
//              -> ds_reads -> setprio(1) + 16 MFMA + setprio(0) -> barrier.
// Overwrite safety: slot s-8's last read >=1 phase (>=2 barriers) before stage of s.
__global__ __launch_bounds__(512, 2)
void k1_gemm(const _Float16* __restrict__ x16, const _Float16* __restrict__ w16,
             _Float16* __restrict__ q16, _Float16* __restrict__ k16,
             _Float16* __restrict__ vT)
{
  __shared__ _Float16 As[2][16384];   // 2 x 32KB
  __shared__ _Float16 Bs[2][16384];   // 2 x 32KB   (total 128KB)

  // bijective XCD swizzle: 768 blocks = 8 XCDs x 96; contiguous (stile x 6 ntiles) per XCD
  const int id  = blockIdx.x;
  const int swz = (id & 7) * 96 + (id >> 3);
  const int ntile = swz % 6;
  const int stile = swz / 6;
  const int wsel  = ntile >> 1;
  const bool vpath = (wsel == 2);

  const int tid = threadIdx.x, lane = tid & 63, w = tid >> 6;
  const int l15 = lane & 15, h = lane >> 4;
  const int wm = w >> 2, wn = w & 3;          // 2 x 4 wave grid; wave output 128m x 64n

  const _Float16* xb = x16 + (size_t)stile * 256 * 512;
  const _Float16* wb = w16 + (size_t)ntile * 256 * 512;

  // staging maps: each gl16 covers 64 phys rows x 8 units; thread -> (t6, u8)
  const int t6 = tid >> 3, u8 = tid & 7;
  const int colsw = ((u8 ^ (t6 & 7)) << 3);   // inverse-swizzled source col (fp16 elems)
  const int gA[4] = { t6, 128 + t6, 64 + t6, 192 + t6 };
  int gB[4];
  #pragma unroll
  for (int i = 0; i < 4; ++i) {
    int pp = i * 64 + t6;
    gB[i] = (((pp >> 5) & 3) << 6) + ((pp >> 7) << 5) + (pp & 31);
  }

#define STAGE_A2(par, i0, kc)                                                      \
  { gl16(xb + (size_t)gA[i0] * 512 + (kc) + colsw, &As[par][((i0)*512 + w*64)*8]); \
    gl16(xb + (size_t)gA[(i0)+1] * 512 + (kc) + colsw, &As[par][(((i0)+1)*512 + w*64)*8]); }
#define STAGE_B2(par, i0, kc)                                                      \
  { gl16(wb + (size_t)gB[i0] * 512 + (kc) + colsw, &Bs[par][((i0)*512 + w*64)*8]); \
    gl16(wb + (size_t)gB[(i0)+1] * 512 + (kc) + colsw, &Bs[par][(((i0)+1)*512 + w*64)*8]); }

#define VM_WAIT(n) { asm volatile("s_waitcnt vmcnt(" #n ")" ::: "memory"); }
#define BAR_PUB()  { __builtin_amdgcn_s_barrier(); __builtin_amdgcn_sched_barrier(0); }
#define BAR_END()  { __builtin_amdgcn_sched_barrier(0); __builtin_amdgcn_s_barrier(); }

  f32x4 acc[8][4] = {};
  half8 af[8], bf0[4], bf1[4];

  // prologue: HTs s=0..4  (A0,B0,B1,A1 of tile0; A0 of tile1)
  STAGE_A2(0, 0, 0);
  STAGE_B2(0, 0, 0);
  STAGE_B2(0, 2, 0);
  STAGE_A2(0, 2, 0);
  STAGE_A2(1, 0, 64);

  #pragma unroll
  for (int t = 0; t < 8; ++t) {
    const int par = t & 1;
    const _Float16* Ap = As[par];
    const _Float16* Bp = Bs[par];
    const int np  = (t + 1) & 1;
    const int kc1 = (t + 1) * 64;

    // -------- phase q0: reads A0,B0 of t; MFMA Q(mh0,nh0); stage B0(t+1) --------
    if (t < 7) { STAGE_B2(np, 0, kc1); VM_WAIT(8); } else { VM_WAIT(4); }
    BAR_PUB();
    #pragma unroll
    for (int m = 0; m < 4; ++m)
      #pragma unroll
      for (int ks = 0; ks < 2; ++ks)
        af[m*2+ks] = ldf64(Ap, wm*64 + m*16 + l15, ks*32 + h*8);
    #pragma unroll
    for (int n = 0; n < 2; ++n)
      #pragma unroll
      for (int ks = 0; ks < 2; ++ks)
        bf0[n*2+ks] = ldf64(Bp, wn*32 + n*16 + l15, ks*32 + h*8);
    __builtin_amdgcn_s_setprio(1);
    #pragma unroll
    for (int m = 0; m < 4; ++m)
      #pragma unroll
      for (int n = 0; n < 2; ++n)
        #pragma unroll
        for (int ks = 0; ks < 2; ++ks)
          acc[m][n] = vpath ? MFMA(bf0[n*2+ks], af[m*2+ks], acc[m][n])
                            : MFMA(af[m*2+ks], bf0[n*2+ks], acc[m][n]);
    __builtin_amdgcn_s_setprio(0);
    BAR_END();

    // -------- phase q1: reads B1 of t; MFMA Q(mh0,nh1); stage B1(t+1) --------
    if (t < 7) { STAGE_B2(np, 2, kc1); VM_WAIT(8); } else { VM_WAIT(2); }
    BAR_PUB();
    #pragma unroll
    for (int n = 0; n < 2; ++n)
      #pragma unroll
      for (int ks = 0; ks < 2; ++ks)
        bf1[n*2+ks] = ldf64(Bp, 128 + wn*32 + n*16 + l15, ks*32 + h*8);
    __builtin_amdgcn_s_setprio(1);
    #pragma unroll
    for (int m = 0; m < 4; ++m)
      #pragma unroll
      for (int n = 0; n < 2; ++n)
        #pragma unroll
        for (int ks = 0; ks < 2; ++ks)
          acc[m][2+n] = vpath ? MFMA(bf1[n*2+ks], af[m*2+ks], acc[m][2+n])
                              : MFMA(af[m*2+ks], bf1[n*2+ks], acc[m][2+n]);
    __builtin_amdgcn_s_setprio(0);
    BAR_END();

    // -------- phase q2: reads A1 of t; MFMA Q(mh1,nh1); stage A1(t+1) --------
    if (t < 7) { STAGE_A2(np, 2, kc1); VM_WAIT(8); } else { VM_WAIT(0); }
    BAR_PUB();
    #pragma unroll
    for (int m = 0; m < 4; ++m)
      #pragma unroll
      for (int ks = 0; ks < 2; ++ks)
        af[m*2+ks] = ldf64(Ap, 128 + wm*64 + m*16 + l15, ks*32 + h*8);
    __builtin_amdgcn_s_setprio(1);
    #pragma unroll
    for (int m = 0; m < 4; ++m)
      #pragma unroll
      for (int n = 0; n < 2; ++n)
        #pragma unroll
        for (int ks = 0; ks < 2; ++ks)
          acc[4+m][2+n] = vpath ? MFMA(bf1[n*2+ks], af[m*2+ks], acc[4+m][2+n])
                                : MFMA(af[m*2+ks], bf1[n*2+ks], acc[4+m][2+n]);
    __builtin_amdgcn_s_setprio(0);
    BAR_END();

    // -------- phase q3: no reads (af half1 + bf0 reused); MFMA Q(mh1,nh0); stage A0(t+2) --------
    if (t < 6) { STAGE_A2(par, 0, (t + 2) * 64); }
    BAR_PUB();
    __builtin_amdgcn_s_setprio(1);
    #pragma unroll
    for (int m = 0; m < 4; ++m)
      #pragma unroll
      for (int n = 0; n < 2; ++n)
        #pragma unroll
        for (int ks = 0; ks < 2; ++ks)
          acc[4+m][n] = vpath ? MFMA(bf0[n*2+ks], af[m*2+ks], acc[4+m][n])
                              : MFMA(af[m*2+ks], bf0[n*2+ks], acc[4+m][n]);
    __builtin_amdgcn_s_setprio(0);
    BAR_END();
  }
#undef STAGE_A2
#undef STAGE_B2
#undef VM_WAIT
#undef BAR_PUB
#undef BAR_END

  if (!vpath) {
    _Float16* dst = (wsel == 0) ? q16 : k16;
    const int m0 = stile * 256 + wm * 128;
    const int n0 = (ntile & 1) * 256 + wn * 64;
    #pragma unroll
    for (int mf = 0; mf < 8; ++mf)
      #pragma unroll
      for (int nf = 0; nf < 4; ++nf)
        #pragma unroll
        for (int r = 0; r < 4; ++r)
          dst[(size_t)(m0 + mf * 16 + h * 4 + r) * 512 + n0 + nf * 16 + l15] =
              (_Float16)acc[mf][nf][r];
  } else {
    const int d0 = (ntile & 1) * 256 + wn * 64;
    const int sg = stile * 256 + wm * 128;
    const int bb = sg >> 13, s0 = sg & 8191;
    _Float16* dst = vT + (size_t)bb * 512 * 8192;
    #pragma unroll
    for (int mf = 0; mf < 8; ++mf)
      #pragma unroll
      for (int nf = 0; nf < 4; ++nf)
        #pragma unroll
        for (int r = 0; r < 4; ++r)
          dst[(size_t)(d0 + nf * 16 + h * 4 + r) * 8192 + s0 + mf * 16 + l15] =
              (_Float16)acc[mf][nf][r];
  }
}

// ================= K2: chunked attention, 4 waves per (b,c), staged k/vT, XCD-chunked =================
__global__ __launch_bounds__(256)
void k2_attn(const _Float16* __restrict__ q16, const _Float16* __restrict__ k16,
             const _Float16* __restrict__ vT, float* __restrict__ out)
{
  __shared__ _Float16 kj[2][128 * 64];   // 2x16KB: S: [128 j][64 e] ; PV: [64 d][128 j]
  __shared__ _Float16 p_lds[64 * 128];   // 16KB, [64 q][128 j], swizzled, wave-local use

  const int id = blockIdx.x;             // 512 blocks = 8 XCDs x 64; contiguous c per XCD
  const int sz = (id & 7) * 64 + (id >> 3);
  const int b = sz >> 7, c = sz & 127;
  const int tid = threadIdx.x, lane = tid & 63, w = tid >> 6;
  const int l15 = lane & 15, h = lane >> 4;
  const int jbase = c * 64 - 64;

  const _Float16* qrow = q16 + (size_t)(b * 8192 + c * 64 + w * 16 + l15) * 512;
  half8 qa[16];
  #pragma unroll
  for (int ks = 0; ks < 16; ++ks) qa[ks] = *(const half8*)(qrow + ks * 32 + h * 8);

  const _Float16* kb = k16 + (size_t)b * 8192 * 512;

  // ---- S phase: e-loop, double-buffered k-slices ----
  f32x4 S[8] = {};
  {
    #pragma unroll
    for (int i = 0; i < 4; ++i) {
      int unit = i * 256 + w * 64 + lane;
      int row = unit >> 3, u = unit & 7;
      int sj = jbase + row; if (sj < 0) sj = 0;
      gl16(kb + (size_t)sj * 512 + ((u ^ (row & 7)) << 3), &kj[0][(i * 256 + w * 64) * 8]);
    }
    int cur = 0;
    for (int ee = 0; ee < 8; ++ee) {
      __syncthreads();                 // drain stage(cur); waves done reading cur^1
      if (ee < 7) {
        #pragma unroll
        for (int i = 0; i < 4; ++i) {
          int unit = i * 256 + w * 64 + lane;
          int row = unit >> 3, u = unit & 7;
          int sj = jbase + row; if (sj < 0) sj = 0;
          gl16(kb + (size_t)sj * 512 + (ee + 1) * 64 + ((u ^ (row & 7)) << 3),
               &kj[cur ^ 1][(i * 256 + w * 64) * 8]);
        }
      }
      #pragma unroll
      for (int ks = 0; ks < 2; ++ks) {
        #pragma unroll
        for (int nt = 0; nt < 8; ++nt) {
          half8 bf = ldf64(kj[cur], nt * 16 + l15, ks * 32 + h * 8);
          S[nt] = MFMA(qa[ee * 2 + ks], bf, S[nt]);
        }
      }
      cur ^= 1;
    }
  }

  // ---- masked softmax ----
  #pragma unroll
  for (int jt = 0; jt < 8; ++jt) {
    int j = jt * 16 + l15;
    #pragma unroll
    for (int r = 0; r < 4; ++r) {
      int ql = w * 16 + h * 4 + r;
      bool valid = (j < 64 + ql) && ((c > 0) || (j >= 64));
      S[jt][r] = valid ? S[jt][r] : -1e30f;
    }
  }
  #pragma unroll
  for (int r = 0; r < 4; ++r) {
    float mx = -1e30f;
    #pragma unroll
    for (int jt = 0; jt < 8; ++jt) mx = fmaxf(mx, S[jt][r]);
    mx = fmaxf(mx, __shfl_xor(mx, 1));
    mx = fmaxf(mx, __shfl_xor(mx, 2));
    mx = fmaxf(mx, __shfl_xor(mx, 4));
    mx = fmaxf(mx, __shfl_xor(mx, 8));
    float sum = 0.f;
    #pragma unroll
    for (int jt = 0; jt < 8; ++jt) {
      float sv = S[jt][r];
      float pe = (sv > -1e29f) ? __expf(sv - mx) : 0.f;
      S[jt][r] = pe;
      sum += pe;
    }
    sum += __shfl_xor(sum, 1);
    sum += __shfl_xor(sum, 2);
    sum += __shfl_xor(sum, 4);
    sum += __shfl_xor(sum, 8);
    float inv = (sum > 0.f) ? (1.0f / sum) : 0.f;   // fully-masked row -> p = 0
    #pragma unroll
    for (int jt = 0; jt < 8; ++jt) {
      int row = w * 16 + h * 4 + r, col = jt * 16 + l15;
      _Float16 ph = (_Float16)(S[jt][r] * inv);
      *(_Float16*)((char*)p_lds + row * 256 + ((col << 1) ^ ((row & 7) << 4))) = ph;
    }
  }
  half8 pa[4];
  #pragma unroll
  for (int ks = 0; ks < 4; ++ks) {
    int row = w * 16 + l15, colh = ks * 32 + h * 8;
    pa[ks] = *(const half8*)((const char*)p_lds + row * 256 + ((colh << 1) ^ ((row & 7) << 4)));
  }

  // ---- PV phase: d-loop, double-buffered vT-slices [64 d][128 j] ----
  const _Float16* vb = vT + (size_t)b * 512 * 8192;
  float* ob = out + (size_t)(b * 8192 + c * 64 + w * 16) * 512;

  __syncthreads();
  #pragma unroll
  for (int i = 0; i < 4; ++i) {
    int unit = i * 256 + w * 64 + lane;
    int row = unit >> 4, u = unit & 15;
    int u2 = (u & 8) | ((u & 7) ^ (row & 7));
    int js = jbase + u2 * 8; if (js < 0) js = 0;
    gl16(vb + (size_t)row * 8192 + js, &kj[0][(i * 256 + w * 64) * 8]);
  }
  int cur = 0;
  for (int dd = 0; dd < 8; ++dd) {
    __syncthreads();
    if (dd < 7) {
      #pragma unroll
      for (int i = 0; i < 4; ++i) {
        int unit = i * 256 + w * 64 + lane;
        int row = unit >> 4, u = unit & 15;
        int u2 = (u & 8) | ((u & 7) ^ (row & 7));
        int js = jbase + u2 * 8; if (js < 0) js = 0;
        gl16(vb + (size_t)((dd + 1) * 64 + row) * 8192 + js, &kj[cur ^ 1][(i * 256 + w * 64) * 8]);
      }
    }
    f32x4 o[4] = {};
    #pragma unroll
    for (int ks = 0; ks < 4; ++ks) {
      #pragma unroll
      for (int nr = 0; nr < 4; ++nr) {
        half8 bf = ldf128(kj[cur], nr * 16 + l15, ks * 32 + h * 8);
        o[nr] = MFMA(pa[ks], bf, o[nr]);
      }
    }
    #pragma unroll
    for (int nr = 0; nr < 4; ++nr)
      #pragma unroll
      for (int r = 0; r < 4; ++r)
        ob[(size_t)(h * 4 + r) * 512 + dd * 64 + nr * 16 + l15] = o[nr][r];
    cur ^= 1;
  }
}

// ================= fallback: round-1 fused kernel (used only if ws too small) =================
__device__ __forceinline__ int swzb(int row, int colByte) {
  return colByte ^ ((row & 7) << 4);
}
__device__ __forceinline__ half8 ldw_frag(const float* __restrict__ W, int row, int e0) {
  const float4* p = reinterpret_cast<const float4*>(W + ((size_t)row << 9) + e0);
  float4 f0 = p[0];
  float4 f1 = p[1];
  half8 v;
  v[0] = (_Float16)f0.x; v[1] = (_Float16)f0.y; v[2] = (_Float16)f0.z; v[3] = (_Float16)f0.w;
  v[4] = (_Float16)f1.x; v[5] = (_Float16)f1.y; v[6] = (_Float16)f1.z; v[7] = (_Float16)f1.w;
  return v;
}
__device__ __forceinline__ half8 ldl_frag(const unsigned short* buf, int row, int col, int strideBytes) {
  int byte = row * strideBytes + swzb(row, col << 1);
  return *reinterpret_cast<const half8*>(reinterpret_cast<const char*>(buf) + byte);
}

__global__ __launch_bounds__(256, 1)
void ep_fused(const float* __restrict__ x, const float* __restrict__ Wq,
              const float* __restrict__ Wk, const float* __restrict__ Wv,
              float* __restrict__ out)
{
  __shared__ unsigned short xs[128 * 512];
  __shared__ unsigned short kv[64 * 128];
  __shared__ unsigned short pq[64 * 128];

  const int bc   = blockIdx.x;
  const int b    = bc >> 7;
  const int c    = bc & 127;
  const int tid  = threadIdx.x;
  const int lane = tid & 63;
  const int w    = tid >> 6;
  const int l15  = lane & 15;
  const int h    = lane >> 4;

  const float* xb = x + (size_t)b * (8192 * 512);
  #pragma unroll
  for (int i = 0; i < 32; ++i) {
    int unit = tid + (i << 8);
    int row  = unit >> 6;
    int e0   = (unit & 63) << 3;
    half8 v;
    if (c == 0 && row < 64) {
      #pragma unroll
      for (int t = 0; t < 8; ++t) v[t] = (_Float16)0.0f;
    } else {
      int s = c * 64 - 64 + row;
      const float4* p = reinterpret_cast<const float4*>(xb + (size_t)s * 512 + e0);
      float4 f0 = p[0], f1 = p[1];
      v[0] = (_Float16)f0.x; v[1] = (_Float16)f0.y; v[2] = (_Float16)f0.z; v[3] = (_Float16)f0.w;
      v[4] = (_Float16)f1.x; v[5] = (_Float16)f1.y; v[6] = (_Float16)f1.z; v[7] = (_Float16)f1.w;
    }
    int byte = (row << 10) + swzb(row, e0 << 1);
    *reinterpret_cast<half8*>(reinterpret_cast<char*>(xs) + byte) = v;
  }
  __syncthreads();

  f32x4 Sacc[8] = {};
  const int d0 = (w << 4) + (h << 2);

  for (int dt = 0; dt < 8; ++dt) {
    const int drow = (dt << 6) + (w << 4) + l15;

    f32x4 qa[4] = {};
    for (int ks = 0; ks < 16; ++ks) {
      half8 a = ldw_frag(Wq, drow, (ks << 5) + (h << 3));
      #pragma unroll
      for (int nt = 0; nt < 4; ++nt) {
        half8 bf = ldl_frag(xs, 64 + (nt << 4) + l15, (ks << 5) + (h << 3), 1024);
        qa[nt] = MFMA(a, bf, qa[nt]);
      }
    }
    #pragma unroll
    for (int nt = 0; nt < 4; ++nt) {
      int q = (nt << 4) + l15;
      half4 hv;
      hv[0] = (_Float16)qa[nt][0]; hv[1] = (_Float16)qa[nt][1];
      hv[2] = (_Float16)qa[nt][2]; hv[3] = (_Float16)qa[nt][3];
      *reinterpret_cast<half4*>(reinterpret_cast<char*>(pq) + q * 128 + swzb(q, d0 << 1)) = hv;
    }

    f32x4 ka[8] = {};
    for (int ks = 0; ks < 16; ++ks) {
      half8 a = ldw_frag(Wk, drow, (ks << 5) + (h << 3));
      #pragma unroll
      for (int nt = 0; nt < 8; ++nt) {
        half8 bf = ldl_frag(xs, (nt << 4) + l15, (ks << 5) + (h << 3), 1024);
        ka[nt] = MFMA(a, bf, ka[nt]);
      }
    }
    #pragma unroll
    for (int nt = 0; nt < 8; ++nt) {
      int j = (nt << 4) + l15;
      half4 hv;
      hv[0] = (_Float16)ka[nt][0]; hv[1] = (_Float16)ka[nt][1];
      hv[2] = (_Float16)ka[nt][2]; hv[3] = (_Float16)ka[nt][3];
      *reinterpret_cast<half4*>(reinterpret_cast<char*>(kv) + j * 128 + swzb(j, d0 << 1)) = hv;
    }
    __syncthreads();

    #pragma unroll
    for (int ksd = 0; ksd < 2; ++ksd) {
      half8 a = ldl_frag(pq, (w << 4) + l15, (ksd << 5) + (h << 3), 128);
      #pragma unroll
      for (int nt = 0; nt < 8; ++nt) {
        half8 bf = ldl_frag(kv, (nt << 4) + l15, (ksd << 5) + (h << 3), 128);
        Sacc[nt] = MFMA(a, bf, Sacc[nt]);
      }
    }
    __syncthreads();
  }

  const float scale = SCALE;
  #pragma unroll
  for (int nt = 0; nt < 8; ++nt) {
    int j = (nt << 4) + l15;
    #pragma unroll
    for (int r = 0; r < 4; ++r) {
      int qrow = (w << 4) + (h << 2) + r;
      bool valid = (j < 64 + qrow) && ((c > 0) || (j >= 64));
      Sacc[nt][r] = valid ? Sacc[nt][r] * scale : -1e30f;
    }
  }
  float inv[4];
  #pragma unroll
  for (int r = 0; r < 4; ++r) {
    float mx = -1e30f;
    #pragma unroll
    for (int nt = 0; nt < 8; ++nt) mx = fmaxf(mx, Sacc[nt][r]);
    mx = fmaxf(mx, __shfl_xor(mx, 1));
    mx = fmaxf(mx, __shfl_xor(mx, 2));
    mx = fmaxf(mx, __shfl_xor(mx, 4));
    mx = fmaxf(mx, __shfl_xor(mx, 8));
    float sum = 0.f;
    #pragma unroll
    for (int nt = 0; nt < 8; ++nt) {
      float sv = Sacc[nt][r];
      float pe = (sv > -1e29f) ? __expf(sv - mx) : 0.f;
      Sacc[nt][r] = pe;
      sum += pe;
    }
    sum += __shfl_xor(sum, 1);
    sum += __shfl_xor(sum, 2);
    sum += __shfl_xor(sum, 4);
    sum += __shfl_xor(sum, 8);
    inv[r] = (sum > 0.f) ? (1.0f / sum) : 0.f;
  }
  #pragma unroll
  for (int nt = 0; nt < 8; ++nt) {
    int j = (nt << 4) + l15;
    #pragma unroll
    for (int r = 0; r < 4; ++r) {
      int qrow = (w << 4) + (h << 2) + r;
      _Float16 ph = (_Float16)(Sacc[nt][r] * inv[r]);
      *reinterpret_cast<_Float16*>(reinterpret_cast<char*>(pq) + qrow * 256 + swzb(qrow, j << 1)) = ph;
    }
  }
  __syncthreads();

  for (int dt = 0; dt < 8; ++dt) {
    const int dcol = (dt << 6) + (w << 4) + l15;

    f32x4 va[8] = {};
    for (int ks = 0; ks < 16; ++ks) {
      half8 bf = ldw_frag(Wv, dcol, (ks << 5) + (h << 3));
      #pragma unroll
      for (int mt = 0; mt < 8; ++mt) {
        half8 a = ldl_frag(xs, (mt << 4) + l15, (ks << 5) + (h << 3), 1024);
        va[mt] = MFMA(a, bf, va[mt]);
      }
    }
    {
      int dl = (w << 4) + l15;
      #pragma unroll
      for (int mt = 0; mt < 8; ++mt) {
        int j0 = (mt << 4) + (h << 2);
        half4 hv;
        hv[0] = (_Float16)va[mt][0]; hv[1] = (_Float16)va[mt][1];
        hv[2] = (_Float16)va[mt][2]; hv[3] = (_Float16)va[mt][3];
        *reinterpret_cast<half4*>(reinterpret_cast<char*>(kv) + dl * 256 + swzb(dl, j0 << 1)) = hv;
      }
    }
    __syncthreads();

    f32x4 oa[4] = {};
    #pragma unroll
    for (int ks = 0; ks < 4; ++ks) {
      half8 a = ldl_frag(pq, (w << 4) + l15, (ks << 5) + (h << 3), 256);
      #pragma unroll
      for (int nt = 0; nt < 4; ++nt) {
        half8 bf = ldl_frag(kv, (nt << 4) + l15, (ks << 5) + (h << 3), 256);
        oa[nt] = MFMA(a, bf, oa[nt]);
      }
    }
    #pragma unroll
    for (int nt = 0; nt < 4; ++nt) {
      int d = (dt << 6) + (nt << 4) + l15;
      #pragma unroll
      for (int r = 0; r < 4; ++r) {
        int qrow = (w << 4) + (h << 2) + r;
        out[((size_t)(b * 8192 + (c << 6) + qrow) << 9) + d] = oa[nt][r];
      }
    }
    __syncthreads();
  }
}

extern "C" void kernel_launch(void* const* d_in, const int* in_sizes, int n_in,
                              void* d_out, int out_size, void* d_ws, size_t ws_size,
                              hipStream_t stream) {
  const float* x  = (const float*)d_in[0];
  const float* Wq = (const float*)d_in[1];
  const float* Wk = (const float*)d_in[2];
  const float* Wv = (const float*)d_in[3];
  float* out = (float*)d_out;
  (void)in_sizes; (void)n_in; (void)out_size;

  if (d_ws != nullptr && ws_size >= WS_NEED) {
    char* ws = (char*)d_ws;
    _Float16* x16 = (_Float16*)(ws + X16_OFF);
    _Float16* q16 = (_Float16*)(ws + Q16_OFF);
    _Float16* k16 = (_Float16*)(ws + K16_OFF);
    _Float16* vT  = (_Float16*)(ws + VT_OFF);
    _Float16* w16 = (_Float16*)(ws + W16_OFF);

    hipLaunchKernelGGL(k0_cvt, dim3(8576), dim3(256), 0, stream, x, Wq, Wk, Wv, x16, w16);
    hipLaunchKernelGGL(k1_gemm, dim3(768), dim3(512), 0, stream, x16, w16, q16, k16, vT);
    hipLaunchKernelGGL(k2_attn, dim3(512), dim3(256), 0, stream, q16, k16, vT, out);
  } else {
    hipLaunchKernelGGL(ep_fused, dim3(512), dim3(256), 0, stream, x, Wq, Wk, Wv, out);
  }
}

// Round 8
// 124.278 us; speedup vs baseline: 1.1155x; 1.0248x over previous
//
#include <hip/hip_runtime.h>

#define SCALE 0.044194173824159216f   // 1/sqrt(512)

typedef _Float16 half8 __attribute__((ext_vector_type(8)));
typedef _Float16 half4 __attribute__((ext_vector_type(4)));
typedef float    f32x4 __attribute__((ext_vector_type(4)));

#define MFMA(A, B, Cc) __builtin_amdgcn_mfma_f32_16x16x32_f16((A), (B), (Cc), 0, 0, 0)

// ---------------- ws layout (bytes) ----------------
#define X16_OFF 0ull
#define Q16_OFF 33554432ull
#define K16_OFF 67108864ull
#define VT_OFF  100663296ull
#define W16_OFF 134217728ull    // W_all fp16 [1536][512]: Wq~(scaled), Wk, Wv
#define WS_NEED 135790592ull

typedef __attribute__((address_space(1))) const unsigned int glb_t;
typedef __attribute__((address_space(3))) unsigned int lds_t;

// async global->LDS, 16B per lane; LDS dest = wave-uniform base + lane*16
__device__ __forceinline__ void gl16(const void* g, void* l) {
  __builtin_amdgcn_global_load_lds((glb_t*)g, (lds_t*)l, 16, 0, 0);
}

// swizzled read of a [R][64] fp16 tile (row stride 128B): LDS[row][u16] = glob[row][u16^(row&7)]
__device__ __forceinline__ half8 ldf64(const _Float16* buf, int row, int colh) {
  int byte = row * 128 + (((colh) << 1) ^ ((row & 7) << 4));
  return *(const half8*)((const char*)buf + byte);
}
// swizzled read of a [R][128] fp16 tile (row stride 256B)
__device__ __forceinline__ half8 ldf128(const _Float16* buf, int row, int colh) {
  int byte = row * 256 + (((colh) << 1) ^ ((row & 7) << 4));
  return *(const half8*)((const char*)buf + byte);
}

// ================= K0: fp32 -> fp16 convert (x; W with 1/sqrt(D) folded into Wq) =================
__global__ __launch_bounds__(256)
void k0_cvt(const float* __restrict__ x, const float* __restrict__ Wq,
            const float* __restrict__ Wk, const float* __restrict__ Wv,
            _Float16* __restrict__ x16, _Float16* __restrict__ w16)
{
  const long long NX = 16777216LL;   // 4*8192*512
  long long base = ((long long)blockIdx.x * 256 + threadIdx.x) * 8;
  const float* src;
  _Float16* dst;
  float sc = 1.0f;
  if (base < NX) {
    src = x + base; dst = x16 + base;
  } else {
    long long o = base - NX;             // 0 .. 786431
    int ws = (int)(o >> 18);
    long long oo = o & 262143LL;
    src = (ws == 0 ? Wq : (ws == 1 ? Wk : Wv)) + oo;
    dst = w16 + o;
    if (ws == 0) sc = SCALE;
  }
  const float4* p = (const float4*)src;
  float4 f0 = p[0], f1 = p[1];
  half8 v;
  v[0] = (_Float16)(f0.x * sc); v[1] = (_Float16)(f0.y * sc);
  v[2] = (_Float16)(f0.z * sc); v[3] = (_Float16)(f0.w * sc);
  v[4] = (_Float16)(f1.x * sc); v[5] = (_Float16)(f1.y * sc);
  v[6] = (_Float16)(f1.z * sc); v[7] = (_Float16)(f1.w * sc);
  *(half8*)dst = v;
}

// ================= K1: 256x256 GEMM, 8 waves, m201-faithful 4-phase/K-tile =================
// C = x16[32768,512] @ W_all[1536,512]^T ; ntile 0..1 -> q, 2..3 -> k, 4..5 -> vT(transposed)
//
// Per phase: {ds_reads (phase start) ; stage 1 HT ; mid-barrier ; setprio+16 MFMA ;
//             counted vmcnt (publish) ; end-barrier}.
// Stage stream per K-tile t: q0:A0(t+1) q1:B0(t+1) q2:B1(t+1) q3:A1(t+1).
// Invariant: 4 loads outstanding entering every phase; all waits vmcnt(4)
// (publishes: q0-end->B1(t), q1-end->A1(t), q3-end->A0,B0(t+1)); taper 2/0 at t=7.
__global__ __launch_bounds__(512, 2)
void k1_gemm(const _Float16* __restrict__ x16, const _Float16* __restrict__ w16,
             _Float16* __restrict__ q16, _Float16* __restrict__ k16,
             _Float16* __restrict__ vT)
{
  __shared__ _Float16 As[2][16384];   // 2 x 32KB
  __shared__ _Float16 Bs[2][16384];   // 2 x 32KB   (total 128KB)

  // bijective XCD swizzle: 768 blocks = 8 XCDs x 96; contiguous (stile x 6 ntiles) per XCD
  const int id  = blockIdx.x;
  const int swz = (id & 7) * 96 + (id >> 3);
  const int ntile = swz % 6;
  const int stile = swz / 6;
  const int wsel  = ntile >> 1;
  const bool vpath = (wsel == 2);

  const int tid = threadIdx.x, lane = tid & 63, w = tid >> 6;
  const int l15 = lane & 15, h = lane >> 4;
  const int wm = w >> 2, wn = w & 3;          // 2 x 4 wave grid; wave output 128m x 64n

  const _Float16* xb = x16 + (size_t)stile * 256 * 512;
  const _Float16* wb = w16 + (size_t)ntile * 256 * 512;

  // staging maps: each STAGE covers 64 phys rows x 8 units; thread -> (t6, u8)
  const int t6 = tid >> 3, u8 = tid & 7;
  const int colsw = ((u8 ^ (t6 & 7)) << 3);   // inverse-swizzled source col (fp16 elems)
  const int gA[4] = { t6, 128 + t6, 64 + t6, 192 + t6 };
  int gB[4];
  #pragma unroll
  for (int i = 0; i < 4; ++i) {
    int pp = i * 64 + t6;
    gB[i] = (((pp >> 5) & 3) << 6) + ((pp >> 7) << 5) + (pp & 31);
  }

#define STAGE_A2(par, i0, kc)                                                      \
  { gl16(xb + (size_t)gA[i0] * 512 + (kc) + colsw, &As[par][((i0)*512 + w*64)*8]); \
    gl16(xb + (size_t)gA[(i0)+1] * 512 + (kc) + colsw, &As[par][(((i0)+1)*512 + w*64)*8]); }
#define STAGE_B2(par, i0, kc)                                                      \
  { gl16(wb + (size_t)gB[i0] * 512 + (kc) + colsw, &Bs[par][((i0)*512 + w*64)*8]); \
    gl16(wb + (size_t)gB[(i0)+1] * 512 + (kc) + colsw, &Bs[par][(((i0)+1)*512 + w*64)*8]); }

#define VM_WAIT(n) { asm volatile("s_waitcnt vmcnt(" #n ")" ::: "memory"); }
#define SBAR()     { __builtin_amdgcn_s_barrier(); }
#define SCHED0()   { __builtin_amdgcn_sched_barrier(0); }

  f32x4 acc[8][4] = {};
  half8 af[8], bf0[4], bf1[4];

  // prologue: tile0's 4 HTs (A0,B0,B1,A1); A0,B0 landed, B1,A1 stay in flight
  STAGE_A2(0, 0, 0);
  STAGE_B2(0, 0, 0);
  STAGE_B2(0, 2, 0);
  STAGE_A2(0, 2, 0);
  VM_WAIT(4);
  SBAR(); SCHED0();

  #pragma unroll
  for (int t = 0; t < 8; ++t) {
    const int par = t & 1;
    const _Float16* Ap = As[par];
    const _Float16* Bp = Bs[par];
    const int np  = par ^ 1;
    const int kc1 = (t + 1) * 64;
    const bool stg = (t < 7);

    // ---- q0: reads A0,B0(t); stage A0(t+1); MFMA Q(mh0,nh0); publish B1(t) ----
    #pragma unroll
    for (int m = 0; m < 4; ++m)
      #pragma unroll
      for (int ks = 0; ks < 2; ++ks)
        af[m*2+ks] = ldf64(Ap, wm*64 + m*16 + l15, ks*32 + h*8);
    #pragma unroll
    for (int n = 0; n < 2; ++n)
      #pragma unroll
      for (int ks = 0; ks < 2; ++ks)
        bf0[n*2+ks] = ldf64(Bp, wn*32 + n*16 + l15, ks*32 + h*8);
    if (stg) STAGE_A2(np, 0, kc1);
    SBAR(); SCHED0();
    __builtin_amdgcn_s_setprio(1);
    #pragma unroll
    for (int m = 0; m < 4; ++m)
      #pragma unroll
      for (int n = 0; n < 2; ++n)
        #pragma unroll
        for (int ks = 0; ks < 2; ++ks)
          acc[m][n] = vpath ? MFMA(bf0[n*2+ks], af[m*2+ks], acc[m][n])
                            : MFMA(af[m*2+ks], bf0[n*2+ks], acc[m][n]);
    __builtin_amdgcn_s_setprio(0);
    SCHED0();
    if (stg) { VM_WAIT(4); } else { VM_WAIT(2); }
    SBAR();

    // ---- q1: reads B1(t); stage B0(t+1); MFMA Q(mh0,nh1); publish A1(t) ----
    #pragma unroll
    for (int n = 0; n < 2; ++n)
      #pragma unroll
      for (int ks = 0; ks < 2; ++ks)
        bf1[n*2+ks] = ldf64(Bp, 128 + wn*32 + n*16 + l15, ks*32 + h*8);
    if (stg) STAGE_B2(np, 0, kc1);
    SBAR(); SCHED0();
    __builtin_amdgcn_s_setprio(1);
    #pragma unroll
    for (int m = 0; m < 4; ++m)
      #pragma unroll
      for (int n = 0; n < 2; ++n)
        #pragma unroll
        for (int ks = 0; ks < 2; ++ks)
          acc[m][2+n] = vpath ? MFMA(bf1[n*2+ks], af[m*2+ks], acc[m][2+n])
                              : MFMA(af[m*2+ks], bf1[n*2+ks], acc[m][2+n]);
    __builtin_amdgcn_s_setprio(0);
    SCHED0();
    if (stg) { VM_WAIT(4); } else { VM_WAIT(0); }
    SBAR();

    // ---- q2: reads A1(t); stage B1(t+1); MFMA Q(mh1,nh1); no publish ----
    #pragma unroll
    for (int m = 0; m < 4; ++m)
      #pragma unroll
      for (int ks = 0; ks < 2; ++ks)
        af[m*2+ks] = ldf64(Ap, 128 + wm*64 + m*16 + l15, ks*32 + h*8);
    if (stg) STAGE_B2(np, 2, kc1);
    SBAR(); SCHED0();
    __builtin_amdgcn_s_setprio(1);
    #pragma unroll
    for (int m = 0; m < 4; ++m)
      #pragma unroll
      for (int n = 0; n < 2; ++n)
        #pragma unroll
        for (int ks = 0; ks < 2; ++ks)
          acc[4+m][2+n] = vpath ? MFMA(bf1[n*2+ks], af[m*2+ks], acc[4+m][2+n])
                                : MFMA(af[m*2+ks], bf1[n*2+ks], acc[4+m][2+n]);
    __builtin_amdgcn_s_setprio(0);
    SCHED0();
    SBAR();

    // ---- q3: no reads (af=A1, bf0 reused); stage A1(t+1); MFMA Q(mh1,nh0); publish A0,B0(t+1) ----
    if (stg) STAGE_A2(np, 2, kc1);
    SBAR(); SCHED0();
    __builtin_amdgcn_s_setprio(1);
    #pragma unroll
    for (int m = 0; m < 4; ++m)
      #pragma unroll
      for (int n = 0; n < 2; ++n)
        #pragma unroll
        for (int ks = 0; ks < 2; ++ks)
          acc[4+m][n] = vpath ? MFMA(bf0[n*2+ks], af[m*2+ks], acc[4+m][n])
                              : MFMA(af[m*2+ks], bf0[n*2+ks], acc[4+m][n]);
    __builtin_amdgcn_s_setprio(0);
    SCHED0();
    if (stg) { VM_WAIT(4); }
    SBAR();
  }
#undef STAGE_A2
#undef STAGE_B2
#undef VM_WAIT
#undef SBAR
#undef SCHED0

  if (!vpath) {
    _Float16* dst = (wsel == 0) ? q16 : k16;
    const int m0 = stile * 256 + wm * 128;
    const int n0 = (ntile & 1) * 256 + wn * 64;
    #pragma unroll
    for (int mf = 0; mf < 8; ++mf)
      #pragma unroll
      for (int nf = 0; nf < 4; ++nf)
        #pragma unroll
        for (int r = 0; r < 4; ++r)
          dst[(size_t)(m0 + mf * 16 + h * 4 + r) * 512 + n0 + nf * 16 + l15] =
              (_Float16)acc[mf][nf][r];
  } else {
    const int d0 = (ntile & 1) * 256 + wn * 64;
    const int sg = stile * 256 + wm * 128;
    const int bb = sg >> 13, s0 = sg & 8191;
    _Float16* dst = vT + (size_t)bb * 512 * 8192;
    #pragma unroll
    for (int mf = 0; mf < 8; ++mf)
      #pragma unroll
      for (int nf = 0; nf < 4; ++nf)
        #pragma unroll
        for (int r = 0; r < 4; ++r)
          dst[(size_t)(d0 + nf * 16 + h * 4 + r) * 8192 + s0 + mf * 16 + l15] =
              (_Float16)acc[mf][nf][r];
  }
}

// ================= K2: chunked attention, 4 waves per (b,c), staged k/vT, XCD-chunked =================
__global__ __launch_bounds__(256)
void k2_attn(const _Float16* __restrict__ q16, const _Float16* __restrict__ k16,
             const _Float16* __restrict__ vT, float* __restrict__ out)
{
  __shared__ _Float16 kj[2][128 * 64];   // 2x16KB: S: [128 j][64 e] ; PV: [64 d][128 j]
  __shared__ _Float16 p_lds[64 * 128];   // 16KB, [64 q][128 j], swizzled, wave-local use

  const int id = blockIdx.x;             // 512 blocks = 8 XCDs x 64; contiguous c per XCD
  const int sz = (id & 7) * 64 + (id >> 3);
  const int b = sz >> 7, c = sz & 127;
  const int tid = threadIdx.x, lane = tid & 63, w = tid >> 6;
  const int l15 = lane & 15, h = lane >> 4;
  const int jbase = c * 64 - 64;

  const _Float16* qrow = q16 + (size_t)(b * 8192 + c * 64 + w * 16 + l15) * 512;
  half8 qa[16];
  #pragma unroll
  for (int ks = 0; ks < 16; ++ks) qa[ks] = *(const half8*)(qrow + ks * 32 + h * 8);

  const _Float16* kb = k16 + (size_t)b * 8192 * 512;

  // ---- S phase: e-loop, double-buffered k-slices ----
  f32x4 S[8] = {};
  {
    #pragma unroll
    for (int i = 0; i < 4; ++i) {
      int unit = i * 256 + w * 64 + lane;
      int row = unit >> 3, u = unit & 7;
      int sj = jbase + row; if (sj < 0) sj = 0;
      gl16(kb + (size_t)sj * 512 + ((u ^ (row & 7)) << 3), &kj[0][(i * 256 + w * 64) * 8]);
    }
    int cur = 0;
    for (int ee = 0; ee < 8; ++ee) {
      __syncthreads();                 // drain stage(cur); waves done reading cur^1
      if (ee < 7) {
        #pragma unroll
        for (int i = 0; i < 4; ++i) {
          int unit = i * 256 + w * 64 + lane;
          int row = unit >> 3, u = unit & 7;
          int sj = jbase + row; if (sj < 0) sj = 0;
          gl16(kb + (size_t)sj * 512 + (ee + 1) * 64 + ((u ^ (row & 7)) << 3),
               &kj[cur ^ 1][(i * 256 + w * 64) * 8]);
        }
      }
      #pragma unroll
      for (int ks = 0; ks < 2; ++ks) {
        #pragma unroll
        for (int nt = 0; nt < 8; ++nt) {
          half8 bf = ldf64(kj[cur], nt * 16 + l15, ks * 32 + h * 8);
          S[nt] = MFMA(qa[ee * 2 + ks], bf, S[nt]);
        }
      }
      cur ^= 1;
    }
  }

  // ---- masked softmax ----
  #pragma unroll
  for (int jt = 0; jt < 8; ++jt) {
    int j = jt * 16 + l15;
    #pragma unroll
    for (int r = 0; r < 4; ++r) {
      int ql = w * 16 + h * 4 + r;
      bool valid = (j < 64 + ql) && ((c > 0) || (j >= 64));
      S[jt][r] = valid ? S[jt][r] : -1e30f;
    }
  }
  #pragma unroll
  for (int r = 0; r < 4; ++r) {
    float mx = -1e30f;
    #pragma unroll
    for (int jt = 0; jt < 8; ++jt) mx = fmaxf(mx, S[jt][r]);
    mx = fmaxf(mx, __shfl_xor(mx, 1));
    mx = fmaxf(mx, __shfl_xor(mx, 2));
    mx = fmaxf(mx, __shfl_xor(mx, 4));
    mx = fmaxf(mx, __shfl_xor(mx, 8));
    float sum = 0.f;
    #pragma unroll
    for (int jt = 0; jt < 8; ++jt) {
      float sv = S[jt][r];
      float pe = (sv > -1e29f) ? __expf(sv - mx) : 0.f;
      S[jt][r] = pe;
      sum += pe;
    }
    sum += __shfl_xor(sum, 1);
    sum += __shfl_xor(sum, 2);
    sum += __shfl_xor(sum, 4);
    sum += __shfl_xor(sum, 8);
    float inv = (sum > 0.f) ? (1.0f / sum) : 0.f;   // fully-masked row -> p = 0
    #pragma unroll
    for (int jt = 0; jt < 8; ++jt) {
      int row = w * 16 + h * 4 + r, col = jt * 16 + l15;
      _Float16 ph = (_Float16)(S[jt][r] * inv);
      *(_Float16*)((char*)p_lds + row * 256 + ((col << 1) ^ ((row & 7) << 4))) = ph;
    }
  }
  half8 pa[4];
  #pragma unroll
  for (int ks = 0; ks < 4; ++ks) {
    int row = w * 16 + l15, colh = ks * 32 + h * 8;
    pa[ks] = *(const half8*)((const char*)p_lds + row * 256 + ((colh << 1) ^ ((row & 7) << 4)));
  }

  // ---- PV phase: d-loop, double-buffered vT-slices [64 d][128 j] ----
  const _Float16* vb = vT + (size_t)b * 512 * 8192;
  float* ob = out + (size_t)(b * 8192 + c * 64 + w * 16) * 512;

  __syncthreads();
  #pragma unroll
  for (int i = 0; i < 4; ++i) {
    int unit = i * 256 + w * 64 + lane;
    int row = unit >> 4, u = unit & 15;
    int u2 = (u & 8) | ((u & 7) ^ (row & 7));
    int js = jbase + u2 * 8; if (js < 0) js = 0;
    gl16(vb + (size_t)row * 8192 + js, &kj[0][(i * 256 + w * 64) * 8]);
  }
  int cur = 0;
  for (int dd = 0; dd < 8; ++dd) {
    __syncthreads();
    if (dd < 7) {
      #pragma unroll
      for (int i = 0; i < 4; ++i) {
        int unit = i * 256 + w * 64 + lane;
        int row = unit >> 4, u = unit & 15;
        int u2 = (u & 8) | ((u & 7) ^ (row & 7));
        int js = jbase + u2 * 8; if (js < 0) js = 0;
        gl16(vb + (size_t)((dd + 1) * 64 + row) * 8192 + js, &kj[cur ^ 1][(i * 256 + w * 64) * 8]);
      }
    }
    f32x4 o[4] = {};
    #pragma unroll
    for (int ks = 0; ks < 4; ++ks) {
      #pragma unroll
      for (int nr = 0; nr < 4; ++nr) {
        half8 bf = ldf128(kj[cur], nr * 16 + l15, ks * 32 + h * 8);
        o[nr] = MFMA(pa[ks], bf, o[nr]);
      }
    }
    #pragma unroll
    for (int nr = 0; nr < 4; ++nr)
      #pragma unroll
      for (int r = 0; r < 4; ++r)
        ob[(size_t)(h * 4 + r) * 512 + dd * 64 + nr * 16 + l15] = o[nr][r];
    cur ^= 1;
  }
}

// ================= fallback: round-1 fused kernel (used only if ws too small) =================
__device__ __forceinline__ int swzb(int row, int colByte) {
  return colByte ^ ((row & 7) << 4);
}
__device__ __forceinline__ half8 ldw_frag(const float* __restrict__ W, int row, int e0) {
  const float4* p = reinterpret_cast<const float4*>(W + ((size_t)row << 9) + e0);
  float4 f0 = p[0];
  float4 f1 = p[1];
  half8 v;
  v[0] = (_Float16)f0.x; v[1] = (_Float16)f0.y; v[2] = (_Float16)f0.z; v[3] = (_Float16)f0.w;
  v[4] = (_Float16)f1.x; v[5] = (_Float16)f1.y; v[6] = (_Float16)f1.z; v[7] = (_Float16)f1.w;
  return v;
}
__device__ __forceinline__ half8 ldl_frag(const unsigned short* buf, int row, int col, int strideBytes) {
  int byte = row * strideBytes + swzb(row, col << 1);
  return *reinterpret_cast<const half8*>(reinterpret_cast<const char*>(buf) + byte);
}

__global__ __launch_bounds__(256, 1)
void ep_fused(const float* __restrict__ x, const float* __restrict__ Wq,
              const float* __restrict__ Wk, const float* __restrict__ Wv,
              float* __restrict__ out)
{
  __shared__ unsigned short xs[128 * 512];
  __shared__ unsigned short kv[64 * 128];
  __shared__ unsigned short pq[64 * 128];

  const int bc   = blockIdx.x;
  const int b    = bc >> 7;
  const int c    = bc & 127;
  const int tid  = threadIdx.x;
  const int lane = tid & 63;
  const int w    = tid >> 6;
  const int l15  = lane & 15;
  const int h    = lane >> 4;

  const float* xb = x + (size_t)b * (8192 * 512);
  #pragma unroll
  for (int i = 0; i < 32; ++i) {
    int unit = tid + (i << 8);
    int row  = unit >> 6;
    int e0   = (unit & 63) << 3;
    half8 v;
    if (c == 0 && row < 64) {
      #pragma unroll
      for (int t = 0; t < 8; ++t) v[t] = (_Float16)0.0f;
    } else {
      int s = c * 64 - 64 + row;
      const float4* p = reinterpret_cast<const float4*>(xb + (size_t)s * 512 + e0);
      float4 f0 = p[0], f1 = p[1];
      v[0] = (_Float16)f0.x; v[1] = (_Float16)f0.y; v[2] = (_Float16)f0.z; v[3] = (_Float16)f0.w;
      v[4] = (_Float16)f1.x; v[5] = (_Float16)f1.y; v[6] = (_Float16)f1.z; v[7] = (_Float16)f1.w;
    }
    int byte = (row << 10) + swzb(row, e0 << 1);
    *reinterpret_cast<half8*>(reinterpret_cast<char*>(xs) + byte) = v;
  }
  __syncthreads();

  f32x4 Sacc[8] = {};
  const int d0 = (w << 4) + (h << 2);

  for (int dt = 0; dt < 8; ++dt) {
    const int drow = (dt << 6) + (w << 4) + l15;

    f32x4 qa[4] = {};
    for (int ks = 0; ks < 16; ++ks) {
      half8 a = ldw_frag(Wq, drow, (ks << 5) + (h << 3));
      #pragma unroll
      for (int nt = 0; nt < 4; ++nt) {
        half8 bf = ldl_frag(xs, 64 + (nt << 4) + l15, (ks << 5) + (h << 3), 1024);
        qa[nt] = MFMA(a, bf, qa[nt]);
      }
    }
    #pragma unroll
    for (int nt = 0; nt < 4; ++nt) {
      int q = (nt << 4) + l15;
      half4 hv;
      hv[0] = (_Float16)qa[nt][0]; hv[1] = (_Float16)qa[nt][1];
      hv[2] = (_Float16)qa[nt][2]; hv[3] = (_Float16)qa[nt][3];
      *reinterpret_cast<half4*>(reinterpret_cast<char*>(pq) + q * 128 + swzb(q, d0 << 1)) = hv;
    }

    f32x4 ka[8] = {};
    for (int ks = 0; ks < 16; ++ks) {
      half8 a = ldw_frag(Wk, drow, (ks << 5) + (h << 3));
      #pragma unroll
      for (int nt = 0; nt < 8; ++nt) {
        half8 bf = ldl_frag(xs, (nt << 4) + l15, (ks << 5) + (h << 3), 1024);
        ka[nt] = MFMA(a, bf, ka[nt]);
      }
    }
    #pragma unroll
    for (int nt = 0; nt < 8; ++nt) {
      int j = (nt << 4) + l15;
      half4 hv;
      hv[0] = (_Float16)ka[nt][0]; hv[1] = (_Float16)ka[nt][1];
      hv[2] = (_Float16)ka[nt][2]; hv[3] = (_Float16)ka[nt][3];
      *reinterpret_cast<half4*>(reinterpret_cast<char*>(kv) + j * 128 + swzb(j, d0 << 1)) = hv;
    }
    __syncthreads();

    #pragma unroll
    for (int ksd = 0; ksd < 2; ++ksd) {
      half8 a = ldl_frag(pq, (w << 4) + l15, (ksd << 5) + (h << 3), 128);
      #pragma unroll
      for (int nt = 0; nt < 8; ++nt) {
        half8 bf = ldl_frag(kv, (nt << 4) + l15, (ksd << 5) + (h << 3), 128);
        Sacc[nt] = MFMA(a, bf, Sacc[nt]);
      }
    }
    __syncthreads();
  }

  const float scale = SCALE;
  #pragma unroll
  for (int nt = 0; nt < 8; ++nt) {
    int j = (nt << 4) + l15;
    #pragma unroll
    for (int r = 0; r < 4; ++r) {
      int qrow = (w << 4) + (h << 2) + r;
      bool valid = (j < 64 + qrow) && ((c > 0) || (j >= 64));
      Sacc[nt][r] = valid ? Sacc[nt][r] * scale : -1e30f;
    }
  }
  float inv[4];
  #pragma unroll
  for (int r = 0; r < 4; ++r) {
    float mx = -1e30f;
    #pragma unroll
    for (int nt = 0; nt < 8; ++nt) mx = fmaxf(mx, Sacc[nt][r]);
    mx = fmaxf(mx, __shfl_xor(mx, 1));
    mx = fmaxf(mx, __shfl_xor(mx, 2));
    mx = fmaxf(mx, __shfl_xor(mx, 4));
    mx = fmaxf(mx, __shfl_xor(mx, 8));
    float sum = 0.f;
    #pragma unroll
    for (int nt = 0; nt < 8; ++nt) {
      float sv = Sacc[nt][r];
      float pe = (sv > -1e29f) ? __expf(sv - mx) : 0.f;
      Sacc[nt][r] = pe;
      sum += pe;
    }
    sum += __shfl_xor(sum, 1);
    sum += __shfl_xor(sum, 2);
    sum += __shfl_xor(sum, 4);
    sum += __shfl_xor(sum, 8);
    inv[r] = (sum > 0.f) ? (1.0f / sum) : 0.f;
  }
  #pragma unroll
  for (int nt = 0; nt < 8; ++nt) {
    int j = (nt << 4) + l15;
    #pragma unroll
    for (int r = 0; r < 4; ++r) {
      int qrow = (w << 4) + (h << 2) + r;
      _Float16 ph = (_Float16)(Sacc[nt][r] * inv[r]);
      *reinterpret_cast<_Float16*>(reinterpret_cast<char*>(pq) + qrow * 256 + swzb(qrow, j << 1)) = ph;
    }
  }
  __syncthreads();

  for (int dt = 0; dt < 8; ++dt) {
    const int dcol = (dt << 6) + (w << 4) + l15;

    f32x4 va[8] = {};
    for (int ks = 0; ks < 16; ++ks) {
      half8 bf = ldw_frag(Wv, dcol, (ks << 5) + (h << 3));
      #pragma unroll
      for (int mt = 0; mt < 8; ++mt) {
        half8 a = ldl_frag(xs, (mt << 4) + l15, (ks << 5) + (h << 3), 1024);
        va[mt] = MFMA(a, bf, va[mt]);
      }
    }
    {
      int dl = (w << 4) + l15;
      #pragma unroll
      for (int mt = 0; mt < 8; ++mt) {
        int j0 = (mt << 4) + (h << 2);
        half4 hv;
        hv[0] = (_Float16)va[mt][0]; hv[1] = (_Float16)va[mt][1];
        hv[2] = (_Float16)va[mt][2]; hv[3] = (_Float16)va[mt][3];
        *reinterpret_cast<half4*>(reinterpret_cast<char*>(kv) + dl * 256 + swzb(dl, j0 << 1)) = hv;
      }
    }
    __syncthreads();

    f32x4 oa[4] = {};
    #pragma unroll
    for (int ks = 0; ks < 4; ++ks) {
      half8 a = ldl_frag(pq, (w << 4) + l15, (ks << 5) + (h << 3), 256);
      #pragma unroll
      for (int nt = 0; nt < 4; ++nt) {
        half8 bf = ldl_frag(kv, (nt << 4) + l15, (ks << 5) + (h << 3), 256);
        oa[nt] = MFMA(a, bf, oa[nt]);
      }
    }
    #pragma unroll
    for (int nt = 0; nt < 4; ++nt) {
      int d = (dt << 6) + (nt << 4) + l15;
      #pragma unroll
      for (int r = 0; r < 4; ++r) {
        int qrow = (w << 4) + (h << 2) + r;
        out[((size_t)(b * 8192 + (c << 6) + qrow) << 9) + d] = oa[nt][r];
      }
    }
    __syncthreads();
  }
}

extern "C" void kernel_launch(void* const* d_in, const int* in_sizes, int n_in,
                              void* d_out, int out_size, void* d_ws, size_t ws_size,
                              hipStream_t stream) {
  const float* x  = (const float*)d_in[0];
  const float* Wq = (const float*)d_in[1];
  const float* Wk = (const float*)d_in[2];
  const float* Wv = (const float*)d_in[3];
  float* out = (float*)d_out;
  (void)in_sizes; (void)n_in; (void)out_size;

  if (d_ws != nullptr && ws_size >= WS_NEED) {
    char* ws = (char*)d_ws;
    _Float16* x16 = (_Float16*)(ws + X16_OFF);
    _Float16* q16 = (_Float16*)(ws + Q16_OFF);
    _Float16* k16 = (_Float16*)(ws + K16_OFF);
    _Float16* vT  = (_Float16*)(ws + VT_OFF);
    _Float16* w16 = (_Float16*)(ws + W16_OFF);

    hipLaunchKernelGGL(k0_cvt, dim3(8576), dim3(256), 0, stream, x, Wq, Wk, Wv, x16, w16);
    hipLaunchKernelGGL(k1_gemm, dim3(768), dim3(512), 0, stream, x16, w16, q16, k16, vT);
    hipLaunchKernelGGL(k2_attn, dim3(512), dim3(256), 0, stream, q16, k16, vT, out);
  } else {
    hipLaunchKernelGGL(ep_fused, dim3(512), dim3(256), 0, stream, x, Wq, Wk, Wv, out);
  }
}